// Round 22
// baseline (187.816 us; speedup 1.0000x reference)
//
#include <hip/hip_runtime.h>
#include <hip/hip_bf16.h>

#define N_NODES 50000
#define N_EDGES 800000
#define D_IN    512
#define D_OUT   256
#define NBLK_SCAN ((N_NODES + 1023) / 1024)   // 49
#define GEMM_NWG (((N_NODES + 127) / 128) * 2)  // 782
#define GEMM_Q   (GEMM_NWG / 8)                  // 97
#define GEMM_R   (GEMM_NWG % 8)                  // 6
#define GATH_CHUNKS ((N_NODES + 63) / 64)        // 782
#define WT_NB    512                             // wt-role blocks in fused wt+count
#define CNT_NB   1563                            // count-role blocks (1563*256*2 >= 800K)

typedef short s8v  __attribute__((ext_vector_type(8)));
typedef float f32x4 __attribute__((ext_vector_type(4)));

__device__ __forceinline__ unsigned short bf16b(float f) {
    __hip_bfloat16 h = __float2bfloat16(f);
    return *reinterpret_cast<unsigned short*>(&h);
}
__device__ __forceinline__ float bflo(unsigned u) { return __uint_as_float(u << 16); }
__device__ __forceinline__ float bfhi(unsigned u) { return __uint_as_float(u & 0xffff0000u); }

// global -> LDS direct copy, 16B per lane; LDS dest arg = wave-uniform base,
// HW adds lane*16.
#define GLD16(gp, lp)                                                           \
    __builtin_amdgcn_global_load_lds(                                           \
        (const __attribute__((address_space(1))) unsigned int*)(const void*)(gp),\
        (__attribute__((address_space(3))) unsigned int*)(void*)(lp), 16, 0, 0)

__device__ __forceinline__ int wave_incl_scan(int v, int lane) {
    #pragma unroll
    for (int d = 1; d < 64; d <<= 1) {
        int u = __shfl_up(v, d, 64);
        if (lane >= d) v += u;
    }
    return v;
}

// ============ FUSED: W transpose/convert + degree count (8-way replicated) ===
// Both roles are LDS-free & low-VGPR -> full occupancy, no scheduling tail
// (round-21 lesson: fusing into the 48KB-LDS gemm displaced blocks at ~60us
// each). cnt8 is zeroed by hipMemsetAsync before this launch (no ordering
// race). bid<512 -> wt role; else count role (1 pass over edges).
__global__ void k_wtcnt(const float* __restrict__ W, unsigned short* __restrict__ Wt,
                        const int* __restrict__ col, int* __restrict__ cnt8) {
    const int bid = blockIdx.x;
    const int t   = threadIdx.x;
    if (bid < WT_NB) {                         // ---- wt role ----
        int k = bid;      // 512
        int n = t;        // 256
        Wt[(size_t)n * D_IN + k] = bf16b(W[(size_t)k * D_OUT + n]);
        return;
    }
    // ---- count role: edge i -> replica i&7 ----
    const int cid = bid - WT_NB;               // 0..CNT_NB-1
    int i = (cid * 256 + t) * 2;
    if (i < N_EDGES) {                         // N_EDGES even; i even
        int2 c = *(const int2*)&col[i];
        atomicAdd(&cnt8[(i & 7) * N_NODES + c.x], 1);
        atomicAdd(&cnt8[((i + 1) & 7) * N_NODES + c.y], 1);
    }
}

__launch_bounds__(256)
__global__ void k_scan1(const int* __restrict__ cnt8, int* __restrict__ bsum) {
    const int t = threadIdx.x, b = blockIdx.x;
    const int idx = b * 1024 + t * 4;
    int s = 0;
    if (idx < N_NODES) {
        #pragma unroll
        for (int q = 0; q < 8; ++q) {
            int4 v = *(const int4*)&cnt8[q * N_NODES + idx];
            s += (v.x + v.y) + (v.z + v.w);
        }
    }
    #pragma unroll
    for (int d = 1; d < 64; d <<= 1) s += __shfl_xor(s, d, 64);
    __shared__ int ws[4];
    if ((t & 63) == 0) ws[t >> 6] = s;
    __syncthreads();
    if (t == 0) bsum[b] = ws[0] + ws[1] + ws[2] + ws[3];
}

// in-block exclusive scan + self-computed block offset; emits row_ptr, dinv,
// and EXACT per-replica cursor bases cursor8[q*N+c] = row_ptr[c]+prefix_q
__launch_bounds__(256)
__global__ void k_scan3(const int* __restrict__ cnt8, const int* __restrict__ bsum,
                        int* __restrict__ row_ptr, float* __restrict__ dinv,
                        int* __restrict__ cursor8) {
    const int t = threadIdx.x, b = blockIdx.x;
    const int lane = t & 63, wv = t >> 6;
    const int idx = b * 1024 + t * 4;
    int4 vq[8];
    int4 tot = make_int4(0, 0, 0, 0);
    if (idx < N_NODES) {
        #pragma unroll
        for (int q = 0; q < 8; ++q) {
            vq[q] = *(const int4*)&cnt8[q * N_NODES + idx];
            tot.x += vq[q].x; tot.y += vq[q].y;
            tot.z += vq[q].z; tot.w += vq[q].w;
        }
    } else {
        #pragma unroll
        for (int q = 0; q < 8; ++q) vq[q] = make_int4(0, 0, 0, 0);
    }
    int s = (tot.x + tot.y) + (tot.z + tot.w);
    int isc = wave_incl_scan(s, lane);
    __shared__ int wsum[4];
    __shared__ int s_boff;
    if (lane == 63) wsum[wv] = isc;
    if (t < 64) {                                  // wave 0: sum of bsum[0..b)
        int u = (t < b) ? bsum[t] : 0;             // b <= 48 < 64
        #pragma unroll
        for (int d = 1; d < 64; d <<= 1) u += __shfl_xor(u, d, 64);
        if (t == 0) s_boff = u;
    }
    __syncthreads();
    int off = s_boff;
    #pragma unroll
    for (int i = 0; i < 4; ++i)
        if (i < wv) off += wsum[i];
    int p0 = off + isc - s;
    int p1 = p0 + tot.x;
    int p2 = p1 + tot.y;
    int p3 = p2 + tot.z;
    if (idx < N_NODES) {
        row_ptr[idx + 0] = p0; dinv[idx + 0] = rsqrtf(1.f + (float)tot.x);
        row_ptr[idx + 1] = p1; dinv[idx + 1] = rsqrtf(1.f + (float)tot.y);
        row_ptr[idx + 2] = p2; dinv[idx + 2] = rsqrtf(1.f + (float)tot.z);
        row_ptr[idx + 3] = p3; dinv[idx + 3] = rsqrtf(1.f + (float)tot.w);
        int4 run = make_int4(p0, p1, p2, p3);
        #pragma unroll
        for (int q = 0; q < 8; ++q) {
            *(int4*)&cursor8[q * N_NODES + idx] = run;
            run.x += vq[q].x; run.y += vq[q].y;
            run.z += vq[q].z; run.w += vq[q].w;
        }
    }
    if (b == 0 && t == 0) row_ptr[N_NODES] = N_EDGES;
}

__global__ void k_fill(const int* __restrict__ row, const int* __restrict__ col,
                       int* __restrict__ cursor8, int* __restrict__ csr_src) {
    int i = (blockIdx.x * 256 + threadIdx.x) * 2;
    if (i < N_EDGES) {
        int2 c = *(const int2*)&col[i];
        int2 r = *(const int2*)&row[i];
        int p0 = atomicAdd(&cursor8[(i & 7) * N_NODES + c.x], 1);
        csr_src[p0] = r.x;
        int p1 = atomicAdd(&cursor8[((i + 1) & 7) * N_NODES + c.y], 1);
        csr_src[p1] = r.y;
    }
}

// ============ MFMA GEMM: yb_blk = bf16(dinv[r] * (x @ W)), COLUMN-BLOCKED ====
// Exact R16/R19 structure (bench floor ~60us for this problem): fp32 A staged
// via global_load_lds, 16B-slot source-side XOR swizzle, BK=64, 48KB single
// buffer; epilogue writes yb[slice][node][32] for the XCD-sliced gather.
__launch_bounds__(256)
__global__ void k_gemm(const float* __restrict__ A,            // [N_NODES,512] fp32
                       const unsigned short* __restrict__ Wt,  // [256,512] bf16
                       const float* __restrict__ dinv,
                       unsigned short* __restrict__ yb)        // [8][N_NODES][32] bf16
{
    __shared__ __align__(16) float          As[128 * 64];   // 32 KB, [m][64k] fp32
    __shared__ __align__(16) unsigned short Bs[128 * 64];   // 16 KB, [n][64k] bf16

    // bijective XCD swizzle (m204)
    int orig = blockIdx.x;
    int xcd = orig % 8, pos = orig / 8;
    int wg = (xcd < GEMM_R) ? xcd * (GEMM_Q + 1) + pos
                            : GEMM_R * (GEMM_Q + 1) + (xcd - GEMM_R) * GEMM_Q + pos;
    const int nt = wg & 1;
    const int mt = wg >> 1;
    const int m0 = mt * 128;
    const int n0 = nt * 128;

    const int t  = threadIdx.x;
    const int w  = t >> 6;
    const int l  = t & 63;
    const int wm = (w >> 1) * 64;
    const int wn = (w & 1) * 64;
    const int lr = l & 15;
    const int lk = l >> 4;

    // A staging: lane l -> LDS row rowbase+(l>>4), dest 16B-slot l&15;
    // source 16B-slot = (l&15) ^ (row&7)
    size_t aoff[8];
    #pragma unroll
    for (int i = 0; i < 8; ++i) {
        int rw = m0 + w * 32 + i * 4 + (l >> 4);
        if (rw >= N_NODES) rw = 0;             // tail clamp; outputs guarded
        int sslot = (l & 15) ^ (rw & 7);
        aoff[i] = (size_t)rw * D_IN + sslot * 4;   // float units
    }
    // B staging (bf16, 16B-chunk swizzle, zero-conflict since R7)
    const int srow = l >> 3;
    const int srcj = (l & 7) ^ srow;
    size_t boff[4];
    #pragma unroll
    for (int i = 0; i < 4; ++i) {
        int g = w * 4 + i;
        int bn = n0 + g * 8 + srow;
        boff[i] = (size_t)bn * D_IN + srcj * 8;
    }

    f32x4 acc[4][4] = {};

    for (int kk = 0; kk < D_IN; kk += 64) {
        #pragma unroll
        for (int i = 0; i < 8; ++i)
            GLD16(&A[aoff[i] + kk], (char*)As + (w * 32 + i * 4) * 256);
        #pragma unroll
        for (int i = 0; i < 4; ++i)
            GLD16(&Wt[boff[i] + kk], (char*)Bs + (w * 4 + i) * 1024);
        __syncthreads();

        #pragma unroll
        for (int ks = 0; ks < 2; ++ks) {
            s8v af[4], bfr[4];
            #pragma unroll
            for (int f = 0; f < 4; ++f) {
                int rw = wm + f * 16 + lr;            // row&7 == lr&7
                int a  = (ks * 4 + lk) * 2;           // logical 16B slot (even)
                int s0 = a ^ (lr & 7);
                int s1 = (a + 1) ^ (lr & 7);          // = s0 ^ 1
                const char* pr = (const char*)As + rw * 256;
                float4 x0 = *(const float4*)(pr + s0 * 16);
                float4 x1 = *(const float4*)(pr + s1 * 16);
                union { s8v v; unsigned short h[8]; } u;
                u.h[0] = bf16b(x0.x); u.h[1] = bf16b(x0.y);
                u.h[2] = bf16b(x0.z); u.h[3] = bf16b(x0.w);
                u.h[4] = bf16b(x1.x); u.h[5] = bf16b(x1.y);
                u.h[6] = bf16b(x1.z); u.h[7] = bf16b(x1.w);
                af[f] = u.v;
            }
            const int kb = (ks * 64 + lk * 16) ^ ((lr & 7) << 4);
            #pragma unroll
            for (int f = 0; f < 4; ++f)
                bfr[f] = *(const s8v*)((const char*)Bs + ((wn + f * 16 + lr) * 128 + kb));
            #pragma unroll
            for (int fm = 0; fm < 4; ++fm)
                #pragma unroll
                for (int fn = 0; fn < 4; ++fn)
                    acc[fm][fn] = __builtin_amdgcn_mfma_f32_16x16x32_bf16(
                        af[fm], bfr[fn], acc[fm][fn], 0, 0, 0);
        }
        __syncthreads();
    }

    #pragma unroll
    for (int fm = 0; fm < 4; ++fm) {
        #pragma unroll
        for (int j = 0; j < 4; ++j) {
            int rw = m0 + wm + fm * 16 + lk * 4 + j;
            if (rw < N_NODES) {
                float s = dinv[rw];
                #pragma unroll
                for (int fn = 0; fn < 4; ++fn) {
                    int cl = n0 + wn + fn * 16 + lr;
                    size_t off = (size_t)(cl >> 5) * (N_NODES * 32)
                               + (size_t)rw * 32 + (cl & 31);
                    yb[off] = bf16b(acc[fm][fn][j] * s);
                }
            }
        }
    }
}

// ============ gather (column-partitioned, rounds of 8) — R21 kernel ==========
// slice = bid%8 keeps each XCD in its 3.2MB L2-resident column slice;
// 4-lane groups, group = one target, lane = one 16B col-slot; rounds of 8
// edges in flight (R21 win: ~13us vs rounds of 4).
__device__ __forceinline__ void add8(float* acc, uint4 q) {
    unsigned x;
    x = q.x; acc[0] += bflo(x); acc[1] += bfhi(x);
    x = q.y; acc[2] += bflo(x); acc[3] += bfhi(x);
    x = q.z; acc[4] += bflo(x); acc[5] += bfhi(x);
    x = q.w; acc[6] += bflo(x); acc[7] += bfhi(x);
}

__launch_bounds__(256)
__global__ void k_gather(const int* __restrict__ row_ptr, const int* __restrict__ csr_src,
                         const unsigned short* __restrict__ yb,   // [8][N_NODES][32]
                         const float* __restrict__ dinv,
                         const float* __restrict__ bias, float* __restrict__ out)
{
    const int s     = blockIdx.x & 7;          // slice -> XCD (dispatch %8)
    const int chunk = blockIdx.x >> 3;
    const int g     = threadIdx.x >> 2;        // group 0..63 = target
    const int cs    = threadIdx.x & 3;         // 16B col-slot within slice
    const int c     = chunk * 64 + g;
    if (c >= N_NODES) return;

    const uint4* t4 = (const uint4*)(yb + (size_t)s * N_NODES * 32);  // 4 uint4/node

    float acc[8] = {0.f,0.f,0.f,0.f,0.f,0.f,0.f,0.f};

    const int e0 = row_ptr[c];
    const int e1 = row_ptr[c + 1];
    for (int i = e0; i < e1; i += 8) {
        int idx[8];
        #pragma unroll
        for (int j = 0; j < 8; ++j) {
            int p = i + j;
            idx[j] = csr_src[p < e1 ? p : e1 - 1];   // clamp: L1-hot re-read
        }
        uint4 v[8];
        #pragma unroll
        for (int j = 0; j < 8; ++j) v[j] = t4[(size_t)idx[j] * 4 + cs];
        #pragma unroll
        for (int j = 0; j < 8; ++j)
            if (i + j < e1) add8(acc, v[j]);         // group-uniform predicate
    }

    add8(acc, t4[(size_t)c * 4 + cs]);               // self-loop term

    const float sc = dinv[c];
    const int colb = s * 32 + cs * 8;
    float4 b0 = *(const float4*)&bias[colb];
    float4 b1 = *(const float4*)&bias[colb + 4];
    float4 o0, o1;
    o0.x = fmaxf(fmaf(acc[0], sc, b0.x), 0.f);
    o0.y = fmaxf(fmaf(acc[1], sc, b0.y), 0.f);
    o0.z = fmaxf(fmaf(acc[2], sc, b0.z), 0.f);
    o0.w = fmaxf(fmaf(acc[3], sc, b0.w), 0.f);
    o1.x = fmaxf(fmaf(acc[4], sc, b1.x), 0.f);
    o1.y = fmaxf(fmaf(acc[5], sc, b1.y), 0.f);
    o1.z = fmaxf(fmaf(acc[6], sc, b1.z), 0.f);
    o1.w = fmaxf(fmaf(acc[7], sc, b1.w), 0.f);
    float* dst = &out[(size_t)c * D_OUT + colb];
    *(float4*)dst       = o0;
    *(float4*)(dst + 4) = o1;
}

extern "C" void kernel_launch(void* const* d_in, const int* in_sizes, int n_in,
                              void* d_out, int out_size, void* d_ws, size_t ws_size,
                              hipStream_t stream) {
    const float* x   = (const float*)d_in[0];
    const int*   ei  = (const int*)d_in[1];
    const float* W   = (const float*)d_in[2];
    const float* b   = (const float*)d_in[3];
    float*       out = (float*)d_out;

    const int* row = ei;
    const int* col = ei + N_EDGES;

    char* p = (char*)d_ws;
    unsigned short* yb = (unsigned short*)p;  p += (size_t)N_NODES * D_OUT * 2;   // 25.6 MB
    unsigned short* Wt = (unsigned short*)p;  p += (size_t)D_OUT * D_IN * 2;      // 256 KB
    int*   csr_src = (int*)p;                 p += (size_t)N_EDGES * 4;           // 3.2 MB
    int*   cnt8    = (int*)p;                 p += (size_t)8 * N_NODES * 4;       // 1.6 MB
    int*   row_ptr = (int*)p;                 p += (size_t)(N_NODES + 4) * 4;
    int*   cursor8 = (int*)p;                 p += (size_t)8 * N_NODES * 4;       // 1.6 MB
    float* dinv    = (float*)p;               p += (size_t)N_NODES * 4;
    int*   bsum    = (int*)p;                 p += (size_t)NBLK_SCAN * 4;

    hipMemsetAsync(cnt8, 0, (size_t)8 * N_NODES * sizeof(int), stream);
    k_wtcnt<<<WT_NB + CNT_NB, 256, 0, stream>>>(W, Wt, col, cnt8);   // wt || count
    k_scan1<<<NBLK_SCAN, 256, 0, stream>>>(cnt8, bsum);
    k_scan3<<<NBLK_SCAN, 256, 0, stream>>>(cnt8, bsum, row_ptr, dinv, cursor8);
    k_fill <<<(N_EDGES / 2 + 255) / 256, 256, 0, stream>>>(row, col, cursor8, csr_src);

    k_gemm<<<GEMM_NWG, 256, 0, stream>>>(x, Wt, dinv, yb);

    k_gather<<<GATH_CHUNKS * 8, 256, 0, stream>>>(row_ptr, csr_src, yb, dinv, b, out);
}

// Round 23
// 182.868 us; speedup vs baseline: 1.0271x; 1.0271x over previous
//
#include <hip/hip_runtime.h>
#include <hip/hip_bf16.h>

#define N_NODES 50000
#define N_EDGES 800000
#define D_IN    512
#define D_OUT   256
#define NBLK_SCAN ((N_NODES + 1023) / 1024)   // 49
#define GEMM_NWG (((N_NODES + 127) / 128) * 2)  // 782
#define GEMM_Q   (GEMM_NWG / 8)                  // 97
#define GEMM_R   (GEMM_NWG % 8)                  // 6
#define GATH_CHUNKS ((N_NODES + 63) / 64)        // 782
#define WT_NB    512                             // wt-role blocks in fused wt+count
#define CNT_NB   1563                            // count-role blocks (1563*256*2 >= 800K)

typedef short s8v  __attribute__((ext_vector_type(8)));
typedef float f32x4 __attribute__((ext_vector_type(4)));

__device__ __forceinline__ unsigned short bf16b(float f) {
    __hip_bfloat16 h = __float2bfloat16(f);
    return *reinterpret_cast<unsigned short*>(&h);
}
__device__ __forceinline__ float bflo(unsigned u) { return __uint_as_float(u << 16); }
__device__ __forceinline__ float bfhi(unsigned u) { return __uint_as_float(u & 0xffff0000u); }

// global -> LDS direct copy, 16B per lane; LDS dest arg = wave-uniform base,
// HW adds lane*16.
#define GLD16(gp, lp)                                                           \
    __builtin_amdgcn_global_load_lds(                                           \
        (const __attribute__((address_space(1))) unsigned int*)(const void*)(gp),\
        (__attribute__((address_space(3))) unsigned int*)(void*)(lp), 16, 0, 0)

__device__ __forceinline__ int wave_incl_scan(int v, int lane) {
    #pragma unroll
    for (int d = 1; d < 64; d <<= 1) {
        int u = __shfl_up(v, d, 64);
        if (lane >= d) v += u;
    }
    return v;
}

// ============ zero cnt8 (round-22 lesson: rocclr fillBufferAligned for this
// 1.6MB memset cost ~25-60us/replay; a plain int4 store kernel is ~4us) ======
__global__ void k_zero(int4* __restrict__ cnt8v) {
    int i = blockIdx.x * 256 + threadIdx.x;       // 100000 int4 = 1.6MB
    if (i < (8 * N_NODES) / 4) cnt8v[i] = make_int4(0, 0, 0, 0);
}

// ============ FUSED: W transpose/convert + degree count (8-way replicated) ===
// Both roles are LDS-free & low-VGPR -> full occupancy, no scheduling tail.
// bid<512 -> wt role; else count role (1 pass over edges).
__global__ void k_wtcnt(const float* __restrict__ W, unsigned short* __restrict__ Wt,
                        const int* __restrict__ col, int* __restrict__ cnt8) {
    const int bid = blockIdx.x;
    const int t   = threadIdx.x;
    if (bid < WT_NB) {                         // ---- wt role ----
        int k = bid;      // 512
        int n = t;        // 256
        Wt[(size_t)n * D_IN + k] = bf16b(W[(size_t)k * D_OUT + n]);
        return;
    }
    // ---- count role: edge i -> replica i&7 ----
    const int cid = bid - WT_NB;               // 0..CNT_NB-1
    int i = (cid * 256 + t) * 2;
    if (i < N_EDGES) {                         // N_EDGES even; i even
        int2 c = *(const int2*)&col[i];
        atomicAdd(&cnt8[(i & 7) * N_NODES + c.x], 1);
        atomicAdd(&cnt8[((i + 1) & 7) * N_NODES + c.y], 1);
    }
}

__launch_bounds__(256)
__global__ void k_scan1(const int* __restrict__ cnt8, int* __restrict__ bsum) {
    const int t = threadIdx.x, b = blockIdx.x;
    const int idx = b * 1024 + t * 4;
    int s = 0;
    if (idx < N_NODES) {
        #pragma unroll
        for (int q = 0; q < 8; ++q) {
            int4 v = *(const int4*)&cnt8[q * N_NODES + idx];
            s += (v.x + v.y) + (v.z + v.w);
        }
    }
    #pragma unroll
    for (int d = 1; d < 64; d <<= 1) s += __shfl_xor(s, d, 64);
    __shared__ int ws[4];
    if ((t & 63) == 0) ws[t >> 6] = s;
    __syncthreads();
    if (t == 0) bsum[b] = ws[0] + ws[1] + ws[2] + ws[3];
}

// in-block exclusive scan + self-computed block offset; emits row_ptr, dinv,
// and EXACT per-replica cursor bases cursor8[q*N+c] = row_ptr[c]+prefix_q
__launch_bounds__(256)
__global__ void k_scan3(const int* __restrict__ cnt8, const int* __restrict__ bsum,
                        int* __restrict__ row_ptr, float* __restrict__ dinv,
                        int* __restrict__ cursor8) {
    const int t = threadIdx.x, b = blockIdx.x;
    const int lane = t & 63, wv = t >> 6;
    const int idx = b * 1024 + t * 4;
    int4 vq[8];
    int4 tot = make_int4(0, 0, 0, 0);
    if (idx < N_NODES) {
        #pragma unroll
        for (int q = 0; q < 8; ++q) {
            vq[q] = *(const int4*)&cnt8[q * N_NODES + idx];
            tot.x += vq[q].x; tot.y += vq[q].y;
            tot.z += vq[q].z; tot.w += vq[q].w;
        }
    } else {
        #pragma unroll
        for (int q = 0; q < 8; ++q) vq[q] = make_int4(0, 0, 0, 0);
    }
    int s = (tot.x + tot.y) + (tot.z + tot.w);
    int isc = wave_incl_scan(s, lane);
    __shared__ int wsum[4];
    __shared__ int s_boff;
    if (lane == 63) wsum[wv] = isc;
    if (t < 64) {                                  // wave 0: sum of bsum[0..b)
        int u = (t < b) ? bsum[t] : 0;             // b <= 48 < 64
        #pragma unroll
        for (int d = 1; d < 64; d <<= 1) u += __shfl_xor(u, d, 64);
        if (t == 0) s_boff = u;
    }
    __syncthreads();
    int off = s_boff;
    #pragma unroll
    for (int i = 0; i < 4; ++i)
        if (i < wv) off += wsum[i];
    int p0 = off + isc - s;
    int p1 = p0 + tot.x;
    int p2 = p1 + tot.y;
    int p3 = p2 + tot.z;
    if (idx < N_NODES) {
        row_ptr[idx + 0] = p0; dinv[idx + 0] = rsqrtf(1.f + (float)tot.x);
        row_ptr[idx + 1] = p1; dinv[idx + 1] = rsqrtf(1.f + (float)tot.y);
        row_ptr[idx + 2] = p2; dinv[idx + 2] = rsqrtf(1.f + (float)tot.z);
        row_ptr[idx + 3] = p3; dinv[idx + 3] = rsqrtf(1.f + (float)tot.w);
        int4 run = make_int4(p0, p1, p2, p3);
        #pragma unroll
        for (int q = 0; q < 8; ++q) {
            *(int4*)&cursor8[q * N_NODES + idx] = run;
            run.x += vq[q].x; run.y += vq[q].y;
            run.z += vq[q].z; run.w += vq[q].w;
        }
    }
    if (b == 0 && t == 0) row_ptr[N_NODES] = N_EDGES;
}

__global__ void k_fill(const int* __restrict__ row, const int* __restrict__ col,
                       int* __restrict__ cursor8, int* __restrict__ csr_src) {
    int i = (blockIdx.x * 256 + threadIdx.x) * 2;
    if (i < N_EDGES) {
        int2 c = *(const int2*)&col[i];
        int2 r = *(const int2*)&row[i];
        int p0 = atomicAdd(&cursor8[(i & 7) * N_NODES + c.x], 1);
        csr_src[p0] = r.x;
        int p1 = atomicAdd(&cursor8[((i + 1) & 7) * N_NODES + c.y], 1);
        csr_src[p1] = r.y;
    }
}

// ============ MFMA GEMM: yb_blk = bf16(dinv[r] * (x @ W)), COLUMN-BLOCKED ====
// Exact R16/R19 structure (bench floor ~60us for this problem): fp32 A staged
// via global_load_lds, 16B-slot source-side XOR swizzle, BK=64, 48KB single
// buffer; epilogue writes yb[slice][node][32] for the XCD-sliced gather.
__launch_bounds__(256)
__global__ void k_gemm(const float* __restrict__ A,            // [N_NODES,512] fp32
                       const unsigned short* __restrict__ Wt,  // [256,512] bf16
                       const float* __restrict__ dinv,
                       unsigned short* __restrict__ yb)        // [8][N_NODES][32] bf16
{
    __shared__ __align__(16) float          As[128 * 64];   // 32 KB, [m][64k] fp32
    __shared__ __align__(16) unsigned short Bs[128 * 64];   // 16 KB, [n][64k] bf16

    // bijective XCD swizzle (m204)
    int orig = blockIdx.x;
    int xcd = orig % 8, pos = orig / 8;
    int wg = (xcd < GEMM_R) ? xcd * (GEMM_Q + 1) + pos
                            : GEMM_R * (GEMM_Q + 1) + (xcd - GEMM_R) * GEMM_Q + pos;
    const int nt = wg & 1;
    const int mt = wg >> 1;
    const int m0 = mt * 128;
    const int n0 = nt * 128;

    const int t  = threadIdx.x;
    const int w  = t >> 6;
    const int l  = t & 63;
    const int wm = (w >> 1) * 64;
    const int wn = (w & 1) * 64;
    const int lr = l & 15;
    const int lk = l >> 4;

    // A staging: lane l -> LDS row rowbase+(l>>4), dest 16B-slot l&15;
    // source 16B-slot = (l&15) ^ (row&7)
    size_t aoff[8];
    #pragma unroll
    for (int i = 0; i < 8; ++i) {
        int rw = m0 + w * 32 + i * 4 + (l >> 4);
        if (rw >= N_NODES) rw = 0;             // tail clamp; outputs guarded
        int sslot = (l & 15) ^ (rw & 7);
        aoff[i] = (size_t)rw * D_IN + sslot * 4;   // float units
    }
    // B staging (bf16, 16B-chunk swizzle, zero-conflict since R7)
    const int srow = l >> 3;
    const int srcj = (l & 7) ^ srow;
    size_t boff[4];
    #pragma unroll
    for (int i = 0; i < 4; ++i) {
        int g = w * 4 + i;
        int bn = n0 + g * 8 + srow;
        boff[i] = (size_t)bn * D_IN + srcj * 8;
    }

    f32x4 acc[4][4] = {};

    for (int kk = 0; kk < D_IN; kk += 64) {
        #pragma unroll
        for (int i = 0; i < 8; ++i)
            GLD16(&A[aoff[i] + kk], (char*)As + (w * 32 + i * 4) * 256);
        #pragma unroll
        for (int i = 0; i < 4; ++i)
            GLD16(&Wt[boff[i] + kk], (char*)Bs + (w * 4 + i) * 1024);
        __syncthreads();

        #pragma unroll
        for (int ks = 0; ks < 2; ++ks) {
            s8v af[4], bfr[4];
            #pragma unroll
            for (int f = 0; f < 4; ++f) {
                int rw = wm + f * 16 + lr;            // row&7 == lr&7
                int a  = (ks * 4 + lk) * 2;           // logical 16B slot (even)
                int s0 = a ^ (lr & 7);
                int s1 = (a + 1) ^ (lr & 7);          // = s0 ^ 1
                const char* pr = (const char*)As + rw * 256;
                float4 x0 = *(const float4*)(pr + s0 * 16);
                float4 x1 = *(const float4*)(pr + s1 * 16);
                union { s8v v; unsigned short h[8]; } u;
                u.h[0] = bf16b(x0.x); u.h[1] = bf16b(x0.y);
                u.h[2] = bf16b(x0.z); u.h[3] = bf16b(x0.w);
                u.h[4] = bf16b(x1.x); u.h[5] = bf16b(x1.y);
                u.h[6] = bf16b(x1.z); u.h[7] = bf16b(x1.w);
                af[f] = u.v;
            }
            const int kb = (ks * 64 + lk * 16) ^ ((lr & 7) << 4);
            #pragma unroll
            for (int f = 0; f < 4; ++f)
                bfr[f] = *(const s8v*)((const char*)Bs + ((wn + f * 16 + lr) * 128 + kb));
            #pragma unroll
            for (int fm = 0; fm < 4; ++fm)
                #pragma unroll
                for (int fn = 0; fn < 4; ++fn)
                    acc[fm][fn] = __builtin_amdgcn_mfma_f32_16x16x32_bf16(
                        af[fm], bfr[fn], acc[fm][fn], 0, 0, 0);
        }
        __syncthreads();
    }

    #pragma unroll
    for (int fm = 0; fm < 4; ++fm) {
        #pragma unroll
        for (int j = 0; j < 4; ++j) {
            int rw = m0 + wm + fm * 16 + lk * 4 + j;
            if (rw < N_NODES) {
                float s = dinv[rw];
                #pragma unroll
                for (int fn = 0; fn < 4; ++fn) {
                    int cl = n0 + wn + fn * 16 + lr;
                    size_t off = (size_t)(cl >> 5) * (N_NODES * 32)
                               + (size_t)rw * 32 + (cl & 31);
                    yb[off] = bf16b(acc[fm][fn][j] * s);
                }
            }
        }
    }
}

// ============ gather (column-partitioned, rounds of 8) ============
// slice = bid%8 keeps each XCD in its 3.2MB L2-resident column slice;
// 4-lane groups, group = one target, lane = one 16B col-slot; rounds of 8
// edges in flight.
__device__ __forceinline__ void add8(float* acc, uint4 q) {
    unsigned x;
    x = q.x; acc[0] += bflo(x); acc[1] += bfhi(x);
    x = q.y; acc[2] += bflo(x); acc[3] += bfhi(x);
    x = q.z; acc[4] += bflo(x); acc[5] += bfhi(x);
    x = q.w; acc[6] += bflo(x); acc[7] += bfhi(x);
}

__launch_bounds__(256)
__global__ void k_gather(const int* __restrict__ row_ptr, const int* __restrict__ csr_src,
                         const unsigned short* __restrict__ yb,   // [8][N_NODES][32]
                         const float* __restrict__ dinv,
                         const float* __restrict__ bias, float* __restrict__ out)
{
    const int s     = blockIdx.x & 7;          // slice -> XCD (dispatch %8)
    const int chunk = blockIdx.x >> 3;
    const int g     = threadIdx.x >> 2;        // group 0..63 = target
    const int cs    = threadIdx.x & 3;         // 16B col-slot within slice
    const int c     = chunk * 64 + g;
    if (c >= N_NODES) return;

    const uint4* t4 = (const uint4*)(yb + (size_t)s * N_NODES * 32);  // 4 uint4/node

    float acc[8] = {0.f,0.f,0.f,0.f,0.f,0.f,0.f,0.f};

    const int e0 = row_ptr[c];
    const int e1 = row_ptr[c + 1];
    for (int i = e0; i < e1; i += 8) {
        int idx[8];
        #pragma unroll
        for (int j = 0; j < 8; ++j) {
            int p = i + j;
            idx[j] = csr_src[p < e1 ? p : e1 - 1];   // clamp: L1-hot re-read
        }
        uint4 v[8];
        #pragma unroll
        for (int j = 0; j < 8; ++j) v[j] = t4[(size_t)idx[j] * 4 + cs];
        #pragma unroll
        for (int j = 0; j < 8; ++j)
            if (i + j < e1) add8(acc, v[j]);         // group-uniform predicate
    }

    add8(acc, t4[(size_t)c * 4 + cs]);               // self-loop term

    const float sc = dinv[c];
    const int colb = s * 32 + cs * 8;
    float4 b0 = *(const float4*)&bias[colb];
    float4 b1 = *(const float4*)&bias[colb + 4];
    float4 o0, o1;
    o0.x = fmaxf(fmaf(acc[0], sc, b0.x), 0.f);
    o0.y = fmaxf(fmaf(acc[1], sc, b0.y), 0.f);
    o0.z = fmaxf(fmaf(acc[2], sc, b0.z), 0.f);
    o0.w = fmaxf(fmaf(acc[3], sc, b0.w), 0.f);
    o1.x = fmaxf(fmaf(acc[4], sc, b1.x), 0.f);
    o1.y = fmaxf(fmaf(acc[5], sc, b1.y), 0.f);
    o1.z = fmaxf(fmaf(acc[6], sc, b1.z), 0.f);
    o1.w = fmaxf(fmaf(acc[7], sc, b1.w), 0.f);
    float* dst = &out[(size_t)c * D_OUT + colb];
    *(float4*)dst       = o0;
    *(float4*)(dst + 4) = o1;
}

extern "C" void kernel_launch(void* const* d_in, const int* in_sizes, int n_in,
                              void* d_out, int out_size, void* d_ws, size_t ws_size,
                              hipStream_t stream) {
    const float* x   = (const float*)d_in[0];
    const int*   ei  = (const int*)d_in[1];
    const float* W   = (const float*)d_in[2];
    const float* b   = (const float*)d_in[3];
    float*       out = (float*)d_out;

    const int* row = ei;
    const int* col = ei + N_EDGES;

    char* p = (char*)d_ws;
    unsigned short* yb = (unsigned short*)p;  p += (size_t)N_NODES * D_OUT * 2;   // 25.6 MB
    unsigned short* Wt = (unsigned short*)p;  p += (size_t)D_OUT * D_IN * 2;      // 256 KB
    int*   csr_src = (int*)p;                 p += (size_t)N_EDGES * 4;           // 3.2 MB
    int*   cnt8    = (int*)p;                 p += (size_t)8 * N_NODES * 4;       // 1.6 MB
    int*   row_ptr = (int*)p;                 p += (size_t)(N_NODES + 4) * 4;
    int*   cursor8 = (int*)p;                 p += (size_t)8 * N_NODES * 4;       // 1.6 MB
    float* dinv    = (float*)p;               p += (size_t)N_NODES * 4;
    int*   bsum    = (int*)p;                 p += (size_t)NBLK_SCAN * 4;

    k_zero <<<(8 * N_NODES / 4 + 255) / 256, 256, 0, stream>>>((int4*)cnt8);
    k_wtcnt<<<WT_NB + CNT_NB, 256, 0, stream>>>(W, Wt, col, cnt8);   // wt || count
    k_scan1<<<NBLK_SCAN, 256, 0, stream>>>(cnt8, bsum);
    k_scan3<<<NBLK_SCAN, 256, 0, stream>>>(cnt8, bsum, row_ptr, dinv, cursor8);
    k_fill <<<(N_EDGES / 2 + 255) / 256, 256, 0, stream>>>(row, col, cursor8, csr_src);

    k_gemm<<<GEMM_NWG, 256, 0, stream>>>(x, Wt, dinv, yb);

    k_gather<<<GATH_CHUNKS * 8, 256, 0, stream>>>(row_ptr, csr_src, yb, dinv, b, out);
}